// Round 13
// baseline (504.955 us; speedup 1.0000x reference)
//
#include <hip/hip_runtime.h>
#include <hip/hip_bf16.h>

#define NN 60000
#define NE 600000
#define DD 128
#define NTOT (NE + NN)
#define NB ((NN + 255) / 256)   // 235 blocks for scan
#define NBK1 ((NN + 63) / 64)   // 938 blocks for bnstat1 / gemm

typedef __attribute__((ext_vector_type(8))) short short8;
typedef __attribute__((ext_vector_type(4))) float f32x4;

__device__ __forceinline__ unsigned short f2bf(float f) {
    unsigned int u = __float_as_uint(f);
    unsigned int r = (u + 0x7FFF + ((u >> 16) & 1)) >> 16;  // RNE
    return (unsigned short)r;
}
__device__ __forceinline__ float bflo(unsigned int u) { return __uint_as_float(u << 16); }
__device__ __forceinline__ float bfhi(unsigned int u) { return __uint_as_float(u & 0xFFFF0000u); }

// ---- degree (edges only; +1 self-loop folded in later) ----
__global__ __launch_bounds__(256) void deg_kernel(const int* __restrict__ dst, int* __restrict__ deg) {
    int e = blockIdx.x * 256 + threadIdx.x;
    if (e < NE) atomicAdd(&deg[dst[e]], 1);
}

// ---- scanA: per-block sums of (deg+1), fused dinv ----
__global__ __launch_bounds__(256) void scanA_kernel(const int* __restrict__ deg, int* __restrict__ partials,
                                                    float* __restrict__ dinv) {
    __shared__ int lds[256];
    int i = blockIdx.x * 256 + threadIdx.x;
    int dv = (i < NN) ? deg[i] : 0;
    if (i < NN) dinv[i] = rsqrtf((float)(dv + 1));
    int v = (i < NN) ? dv + 1 : 0;
    lds[threadIdx.x] = v;
    __syncthreads();
    for (int off = 128; off > 0; off >>= 1) {
        if (threadIdx.x < off) lds[threadIdx.x] += lds[threadIdx.x + off];
        __syncthreads();
    }
    if (threadIdx.x == 0) partials[blockIdx.x] = lds[0];
}

__global__ __launch_bounds__(256) void scanB_kernel(const int* __restrict__ partials,
                                                    int* __restrict__ blockoff,
                                                    int* __restrict__ rowptr) {
    __shared__ int lds[256];
    int t = threadIdx.x;
    int v = (t < NB) ? partials[t] : 0;
    lds[t] = v;
    __syncthreads();
    for (int off = 1; off < 256; off <<= 1) {
        int u = (t >= off) ? lds[t - off] : 0;
        __syncthreads();
        lds[t] += u;
        __syncthreads();
    }
    if (t < NB) blockoff[t] = lds[t] - v;  // exclusive
    if (t == 0) rowptr[NN] = NTOT;
}

__global__ __launch_bounds__(256) void scanC_kernel(const int* __restrict__ deg,
                                                    const int* __restrict__ blockoff,
                                                    int* __restrict__ rowptr) {
    __shared__ int lds[256];
    int i = blockIdx.x * 256 + threadIdx.x;
    int t = threadIdx.x;
    int v = (i < NN) ? deg[i] + 1 : 0;
    lds[t] = v;
    __syncthreads();
    for (int off = 1; off < 256; off <<= 1) {
        int u = (t >= off) ? lds[t - off] : 0;
        __syncthreads();
        lds[t] += u;
        __syncthreads();
    }
    if (i < NN) rowptr[i] = blockoff[blockIdx.x] + lds[t] - v;
}

// ---- CSR fill: packed int2{src, coef_bits} -> ONE 8B scattered store per edge ----
__global__ __launch_bounds__(256) void fill_kernel(const int* __restrict__ src, const int* __restrict__ dst,
                                                   const int* __restrict__ rowptr, int* __restrict__ cursor,
                                                   const float* __restrict__ dinv,
                                                   int2* __restrict__ csr) {
    int e = blockIdx.x * 256 + threadIdx.x;
    if (e >= NTOT) return;
    int s, t;
    if (e < NE) { s = src[e]; t = dst[e]; }
    else { s = t = e - NE; }
    int pos = atomicAdd(&cursor[t], 1);
    int2 rec;
    rec.x = s;
    rec.y = __float_as_int(dinv[s] * dinv[t]);
    csr[rowptr[t] + pos] = rec;
}

// ---- W convert to MFMA-fragment-major order, all 3 layers ----
__global__ __launch_bounds__(256) void wcvt_kernel(const float* __restrict__ W0, const float* __restrict__ W1,
                                                   const float* __restrict__ W2, unsigned short* __restrict__ Wsw) {
    int idx = blockIdx.x * 256 + threadIdx.x;  // 3 * 32 frags * 64 lanes = 6144
    if (idx >= 3 * 32 * 64) return;
    int L = idx >> 11;
    int rem = idx & 2047;
    int frag = rem >> 6;         // 0..31  (kc*8 + nt)
    int lane = rem & 63;
    int kc = frag >> 3, nt = frag & 7;
    int m = lane & 15, q = lane >> 4;
    int n = nt * 16 + m;
    int k0 = kc * 32 + q * 8;
    const float* W = (L == 0) ? W0 : (L == 1) ? W1 : W2;
    unsigned int p[4];
#pragma unroll
    for (int j = 0; j < 4; j++) {
        unsigned int b0 = f2bf(W[(size_t)(k0 + 2 * j) * DD + n]);
        unsigned int b1 = f2bf(W[(size_t)(k0 + 2 * j + 1) * DD + n]);
        p[j] = b0 | (b1 << 16);
    }
    uint4 o; o.x = p[0]; o.y = p[1]; o.z = p[2]; o.w = p[3];
    *(uint4*)(Wsw + ((size_t)L * 2048 + (size_t)frag * 64 + lane) * 8) = o;
}

// ---- MFMA GEMM (R11 coalesced design, unchanged) ----
template <bool BF16IN>
__global__ __launch_bounds__(256) void gemm_mfma_kernel(const void* __restrict__ Ain,
                                                        const unsigned short* __restrict__ Wsw,
                                                        const float* __restrict__ normp,
                                                        unsigned short* __restrict__ C) {
    __shared__ unsigned short Atile[64 * 128];  // 16 KB, swizzled 16B chunks
    __shared__ float rep[4][16][68];            // 17.4 KB, per-wave repack
    int tid = threadIdx.x;
    int wslot = tid >> 6;
    int l = tid & 63;
    int m = l & 15;
    int q = l >> 4;
    int rblk = blockIdx.x * 64;

#pragma unroll
    for (int p = 0; p < 4; p++) {
        int rowl = p * 16 + (tid >> 4);
        int c = tid & 15;
        int row = min(rblk + rowl, NN - 1);
        float a[8];
        if (BF16IN) {
            uint4 u = *(const uint4*)((const unsigned short*)Ain + (size_t)row * DD + c * 8);
            a[0] = bflo(u.x); a[1] = bfhi(u.x); a[2] = bflo(u.y); a[3] = bfhi(u.y);
            a[4] = bflo(u.z); a[5] = bfhi(u.z); a[6] = bflo(u.w); a[7] = bfhi(u.w);
        } else {
            const float* Af = (const float*)Ain + (size_t)row * DD + c * 8;
            float4 x0 = *(const float4*)Af;
            float4 x1 = *(const float4*)(Af + 4);
            a[0] = x0.x; a[1] = x0.y; a[2] = x0.z; a[3] = x0.w;
            a[4] = x1.x; a[5] = x1.y; a[6] = x1.z; a[7] = x1.w;
        }
        if (normp) {
#pragma unroll
            for (int j = 0; j < 8; j++) {
                float v = fmaf(a[j], normp[c * 8 + j], normp[128 + c * 8 + j]);
                a[j] = (v >= 0.f) ? v : 0.01f * v;
            }
        }
        unsigned int w0 = f2bf(a[0]) | ((unsigned int)f2bf(a[1]) << 16);
        unsigned int w1 = f2bf(a[2]) | ((unsigned int)f2bf(a[3]) << 16);
        unsigned int w2 = f2bf(a[4]) | ((unsigned int)f2bf(a[5]) << 16);
        unsigned int w3 = f2bf(a[6]) | ((unsigned int)f2bf(a[7]) << 16);
        uint4 wv; wv.x = w0; wv.y = w1; wv.z = w2; wv.w = w3;
        *(uint4*)&Atile[rowl * 128 + ((c ^ (rowl & 15)) * 8)] = wv;
    }
    __syncthreads();

    f32x4 acc[8];
#pragma unroll
    for (int i = 0; i < 8; i++) acc[i] = (f32x4){0.f, 0.f, 0.f, 0.f};
    int rowl_w = wslot * 16 + m;
#pragma unroll
    for (int kc = 0; kc < 4; kc++) {
        short8 af = *(const short8*)&Atile[rowl_w * 128 + (((kc * 4 + q) ^ m) * 8)];
#pragma unroll
        for (int nt = 0; nt < 8; nt++) {
            short8 bf = *(const short8*)(Wsw + ((size_t)(kc * 8 + nt) * 64 + l) * 8);
            acc[nt] = __builtin_amdgcn_mfma_f32_16x16x32_bf16(af, bf, acc[nt], 0, 0, 0);
        }
    }

    int wrow0 = rblk + wslot * 16;
    int r2 = l >> 2, c2 = l & 3;
#pragma unroll
    for (int pass = 0; pass < 2; pass++) {
#pragma unroll
        for (int ntl = 0; ntl < 4; ntl++) {
            f32x4 a = acc[pass * 4 + ntl];
#pragma unroll
            for (int r = 0; r < 4; r++)
                rep[wslot][q * 4 + r][ntl * 16 + m] = a[r];
        }
        const float* tr = &rep[wslot][r2][c2 * 16];
        float4 v0 = *(const float4*)(tr);
        float4 v1 = *(const float4*)(tr + 4);
        float4 v2 = *(const float4*)(tr + 8);
        float4 v3 = *(const float4*)(tr + 12);
        uint4 oA, oB;
        oA.x = f2bf(v0.x) | ((unsigned int)f2bf(v0.y) << 16);
        oA.y = f2bf(v0.z) | ((unsigned int)f2bf(v0.w) << 16);
        oA.z = f2bf(v1.x) | ((unsigned int)f2bf(v1.y) << 16);
        oA.w = f2bf(v1.z) | ((unsigned int)f2bf(v1.w) << 16);
        oB.x = f2bf(v2.x) | ((unsigned int)f2bf(v2.y) << 16);
        oB.y = f2bf(v2.z) | ((unsigned int)f2bf(v2.w) << 16);
        oB.z = f2bf(v3.x) | ((unsigned int)f2bf(v3.y) << 16);
        oB.w = f2bf(v3.z) | ((unsigned int)f2bf(v3.w) << 16);
        int row = wrow0 + r2;
        if (row < NN) {
            unsigned short* cp = C + (size_t)row * DD + pass * 64 + c2 * 16;
            *(uint4*)cp = oA;
            *(uint4*)(cp + 8) = oB;
        }
    }
}

// ---- CSR gather (R10/R11 known-good): one node/wave, unroll 8 ----
__global__ __launch_bounds__(256) void gather_kernel(const unsigned short* __restrict__ xw,
                                                     const int* __restrict__ rowptr,
                                                     const int2* __restrict__ csr,
                                                     unsigned short* __restrict__ agg) {
    int wid = (int)((blockIdx.x * 256 + threadIdx.x) >> 6);
    int l = threadIdx.x & 63;
    if (wid >= NN) return;
    int beg = rowptr[wid], end = rowptr[wid + 1];
    float ax = 0.f, ay = 0.f;
    int i = beg;
    for (; i + 8 <= end; i += 8) {
        unsigned int u[8];
        float c[8];
#pragma unroll
        for (int j = 0; j < 8; j++) {
            int2 r = csr[i + j];
            u[j] = *(const unsigned int*)(xw + (size_t)r.x * DD + 2 * l);
            c[j] = __int_as_float(r.y);
        }
#pragma unroll
        for (int j = 0; j < 8; j++) {
            ax += bflo(u[j]) * c[j];
            ay += bfhi(u[j]) * c[j];
        }
    }
    for (; i + 2 <= end; i += 2) {
        int2 r0 = csr[i], r1 = csr[i + 1];
        unsigned int u0 = *(const unsigned int*)(xw + (size_t)r0.x * DD + 2 * l);
        unsigned int u1 = *(const unsigned int*)(xw + (size_t)r1.x * DD + 2 * l);
        float c0 = __int_as_float(r0.y), c1 = __int_as_float(r1.y);
        ax += bflo(u0) * c0 + bflo(u1) * c1;
        ay += bfhi(u0) * c0 + bfhi(u1) * c1;
    }
    if (i < end) {
        int2 r0 = csr[i];
        unsigned int u0 = *(const unsigned int*)(xw + (size_t)r0.x * DD + 2 * l);
        float c0 = __int_as_float(r0.y);
        ax += bflo(u0) * c0;
        ay += bfhi(u0) * c0;
    }
    ((unsigned int*)(agg + (size_t)wid * DD))[l] = (unsigned int)f2bf(ax) | ((unsigned int)f2bf(ay) << 16);
}

// ---- BN stats stage 1: per-block partials (NO global atomics — R9 lesson).
// Grid 938, block = 64 rows. Thread: 4 independent coalesced uint4 loads
// (8 features each), register s/q, LDS 16-way reduce, one 1KB partials row.
// Replaces the 235-block latency-starved bnstat (43 us, Occ 7.5% — R12 pmc).
__global__ __launch_bounds__(256) void bnstat1_kernel(const unsigned short* __restrict__ h,
                                                      float* __restrict__ partials) {
    int t = threadIdx.x;
    int rg = t >> 4;       // row group 0..15
    int c  = t & 15;       // feature chunk: features 8c..8c+7
    int rbase = blockIdx.x * 64;
    float s[8], q[8];
#pragma unroll
    for (int j = 0; j < 8; j++) { s[j] = 0.f; q[j] = 0.f; }
#pragma unroll
    for (int p = 0; p < 4; p++) {
        int row = rbase + rg + 16 * p;
        if (row < NN) {
            uint4 u = *(const uint4*)(h + (size_t)row * DD + c * 8);
            float v;
            v = bflo(u.x); s[0] += v; q[0] += v * v;
            v = bfhi(u.x); s[1] += v; q[1] += v * v;
            v = bflo(u.y); s[2] += v; q[2] += v * v;
            v = bfhi(u.y); s[3] += v; q[3] += v * v;
            v = bflo(u.z); s[4] += v; q[4] += v * v;
            v = bfhi(u.z); s[5] += v; q[5] += v * v;
            v = bflo(u.w); s[6] += v; q[6] += v * v;
            v = bfhi(u.w); s[7] += v; q[7] += v * v;
        }
    }
    __shared__ float lds[2][16][128];  // 16 KB
#pragma unroll
    for (int j = 0; j < 8; j++) {
        lds[0][rg][c * 8 + j] = s[j];
        lds[1][rg][c * 8 + j] = q[j];
    }
    __syncthreads();
    int f = t & 127, stat = t >> 7;
    float acc = 0.f;
#pragma unroll
    for (int r = 0; r < 16; r++) acc += lds[stat][r][f];
    partials[(size_t)blockIdx.x * 256 + stat * 128 + f] = acc;  // coalesced 1KB row
}

// ---- BN stats stage 2 + bnfin: one 1024-thread block sweeps partials ----
__global__ __launch_bounds__(1024) void bnred_kernel(const float* __restrict__ partials,
                                                     const float* __restrict__ g,
                                                     const float* __restrict__ be,
                                                     float* __restrict__ normp) {
    int t = threadIdx.x;
    int f2 = t & 255, seg = t >> 8;   // 4 segments
    float acc = 0.f;
    for (int b = seg; b < NBK1; b += 4)
        acc += partials[(size_t)b * 256 + f2];   // coalesced
    __shared__ float lds[4][256];
    lds[seg][f2] = acc;
    __syncthreads();
    __shared__ float tot[256];
    if (t < 256) tot[t] = lds[0][t] + lds[1][t] + lds[2][t] + lds[3][t];
    __syncthreads();
    if (t < 128) {
        float sm = tot[t], sq = tot[128 + t];
        const float invN = 1.0f / (float)NN;
        float mu = sm * invN;
        float var = sq * invN - mu * mu;
        float sc = rsqrtf(var + 1e-5f) * g[t];
        normp[t] = sc;
        normp[128 + t] = be[t] - mu * sc;
    }
}

// ---- final: out_fp32 = bf16(agg)*scale+shift ----
__global__ __launch_bounds__(256) void bnapply_kernel(const unsigned short* __restrict__ h,
                                                      const float* __restrict__ normp,
                                                      float* __restrict__ out) {
    int idx = blockIdx.x * 256 + threadIdx.x;
    if (idx >= NN * DD / 4) return;
    int d = (idx * 4) & 127;
    uint2 u = *(const uint2*)(h + idx * 4);
    float4 sc = *(const float4*)&normp[d];
    float4 sh = *(const float4*)&normp[128 + d];
    float4 o;
    o.x = fmaf(bflo(u.x), sc.x, sh.x);
    o.y = fmaf(bfhi(u.x), sc.y, sh.y);
    o.z = fmaf(bflo(u.y), sc.z, sh.z);
    o.w = fmaf(bfhi(u.y), sc.w, sh.w);
    *(float4*)&out[idx * 4] = o;
}

extern "C" void kernel_launch(void* const* d_in, const int* in_sizes, int n_in,
                              void* d_out, int out_size, void* d_ws, size_t ws_size,
                              hipStream_t stream) {
    const float* x = (const float*)d_in[0];
    const int* ei = (const int*)d_in[1];
    const int* srcp = ei;
    const int* dstp = ei + NE;
    const float* w[3]  = {(const float*)d_in[2], (const float*)d_in[6],  (const float*)d_in[10]};
    const float* g[3]  = {(const float*)d_in[4], (const float*)d_in[8],  (const float*)d_in[12]};
    const float* be[3] = {(const float*)d_in[5], (const float*)d_in[9],  (const float*)d_in[13]};

    // workspace layout (~44 MB), all chunks 16-B aligned
    unsigned short* xwb  = (unsigned short*)d_ws;        // bf16 xw  [NN*DD]
    unsigned short* aggb = xwb + (size_t)NN * DD;        // bf16 agg [NN*DD]
    int* deg    = (int*)(aggb + (size_t)NN * DD);        // [NN]  (one memset: deg+cursor)
    int* cursor = deg + NN;                              // [NN]
    int* rowptr = cursor + NN;                           // [NN+16]
    float* dinv = (float*)(rowptr + NN + 16);            // [NN]
    float* ss   = dinv + NN;                             // [3*256] scale/shift per layer
    int* spart  = (int*)(ss + 3 * 256);                  // [256] scan partials
    int* blockoff = spart + 256;                         // [256]
    float* bnp  = (float*)(blockoff + 256);              // [NBK1*256] bn partials
    unsigned short* Wsw = (unsigned short*)(bnp + (size_t)NBK1 * 256);  // [3*128*128]
    int2* csr = (int2*)(Wsw + 3 * DD * DD);              // [NTOT] packed {src, coef}
    float* out = (float*)d_out;

    // ---- CSR build (once; edge_index constant across layers) ----
    hipMemsetAsync(deg, 0, 2 * NN * sizeof(int), stream);        // deg + cursor
    deg_kernel<<<(NE + 255) / 256, 256, 0, stream>>>(dstp, deg);
    scanA_kernel<<<NB, 256, 0, stream>>>(deg, spart, dinv);
    scanB_kernel<<<1, 256, 0, stream>>>(spart, blockoff, rowptr);
    scanC_kernel<<<NB, 256, 0, stream>>>(deg, blockoff, rowptr);
    fill_kernel<<<(NTOT + 255) / 256, 256, 0, stream>>>(srcp, dstp, rowptr, cursor, dinv, csr);
    wcvt_kernel<<<24, 256, 0, stream>>>(w[0], w[1], w[2], Wsw);

    const int GATHER_GRID = (NN + 3) / 4;       // 15000 (one node per wave)
    for (int L = 0; L < 3; ++L) {
        const float* normp = (L == 0) ? nullptr : (ss + (L - 1) * 256);
        if (L == 0)
            gemm_mfma_kernel<false><<<NBK1, 256, 0, stream>>>(x, Wsw, normp, xwb);
        else
            gemm_mfma_kernel<true><<<NBK1, 256, 0, stream>>>(aggb, Wsw + (size_t)L * DD * DD, normp, xwb);
        gather_kernel<<<GATHER_GRID, 256, 0, stream>>>(xwb, rowptr, csr, aggb);
        bnstat1_kernel<<<NBK1, 256, 0, stream>>>(aggb, bnp);
        bnred_kernel<<<1, 1024, 0, stream>>>(bnp, g[L], be[L], ss + L * 256);
        if (L == 2)
            bnapply_kernel<<<(NN * DD / 4 + 255) / 256, 256, 0, stream>>>(aggb, ss + L * 256, out);
    }
}

// Round 14
// 340.860 us; speedup vs baseline: 1.4814x; 1.4814x over previous
//
#include <hip/hip_runtime.h>
#include <hip/hip_bf16.h>

#define NN 60000
#define NE 600000
#define DD 128
#define NTOT (NE + NN)
#define NB ((NN + 255) / 256)   // 235 blocks for scan
#define NBK1 ((NN + 63) / 64)   // 938 blocks for bnstat1 / gemm
#define RED1 32                 // bnredA blocks

typedef __attribute__((ext_vector_type(8))) short short8;
typedef __attribute__((ext_vector_type(4))) float f32x4;

__device__ __forceinline__ unsigned short f2bf(float f) {
    unsigned int u = __float_as_uint(f);
    unsigned int r = (u + 0x7FFF + ((u >> 16) & 1)) >> 16;  // RNE
    return (unsigned short)r;
}
__device__ __forceinline__ float bflo(unsigned int u) { return __uint_as_float(u << 16); }
__device__ __forceinline__ float bfhi(unsigned int u) { return __uint_as_float(u & 0xFFFF0000u); }

// ---- degree (edges only; +1 self-loop folded in later) ----
__global__ __launch_bounds__(256) void deg_kernel(const int* __restrict__ dst, int* __restrict__ deg) {
    int e = blockIdx.x * 256 + threadIdx.x;
    if (e < NE) atomicAdd(&deg[dst[e]], 1);
}

// ---- scanA: per-block sums of (deg+1), fused dinv ----
__global__ __launch_bounds__(256) void scanA_kernel(const int* __restrict__ deg, int* __restrict__ partials,
                                                    float* __restrict__ dinv) {
    __shared__ int lds[256];
    int i = blockIdx.x * 256 + threadIdx.x;
    int dv = (i < NN) ? deg[i] : 0;
    if (i < NN) dinv[i] = rsqrtf((float)(dv + 1));
    int v = (i < NN) ? dv + 1 : 0;
    lds[threadIdx.x] = v;
    __syncthreads();
    for (int off = 128; off > 0; off >>= 1) {
        if (threadIdx.x < off) lds[threadIdx.x] += lds[threadIdx.x + off];
        __syncthreads();
    }
    if (threadIdx.x == 0) partials[blockIdx.x] = lds[0];
}

__global__ __launch_bounds__(256) void scanB_kernel(const int* __restrict__ partials,
                                                    int* __restrict__ blockoff,
                                                    int* __restrict__ rowptr) {
    __shared__ int lds[256];
    int t = threadIdx.x;
    int v = (t < NB) ? partials[t] : 0;
    lds[t] = v;
    __syncthreads();
    for (int off = 1; off < 256; off <<= 1) {
        int u = (t >= off) ? lds[t - off] : 0;
        __syncthreads();
        lds[t] += u;
        __syncthreads();
    }
    if (t < NB) blockoff[t] = lds[t] - v;  // exclusive
    if (t == 0) rowptr[NN] = NTOT;
}

__global__ __launch_bounds__(256) void scanC_kernel(const int* __restrict__ deg,
                                                    const int* __restrict__ blockoff,
                                                    int* __restrict__ rowptr) {
    __shared__ int lds[256];
    int i = blockIdx.x * 256 + threadIdx.x;
    int t = threadIdx.x;
    int v = (i < NN) ? deg[i] + 1 : 0;
    lds[t] = v;
    __syncthreads();
    for (int off = 1; off < 256; off <<= 1) {
        int u = (t >= off) ? lds[t - off] : 0;
        __syncthreads();
        lds[t] += u;
        __syncthreads();
    }
    if (i < NN) rowptr[i] = blockoff[blockIdx.x] + lds[t] - v;
}

// ---- CSR fill: packed int2{src, coef_bits} -> ONE 8B scattered store per edge ----
__global__ __launch_bounds__(256) void fill_kernel(const int* __restrict__ src, const int* __restrict__ dst,
                                                   const int* __restrict__ rowptr, int* __restrict__ cursor,
                                                   const float* __restrict__ dinv,
                                                   int2* __restrict__ csr) {
    int e = blockIdx.x * 256 + threadIdx.x;
    if (e >= NTOT) return;
    int s, t;
    if (e < NE) { s = src[e]; t = dst[e]; }
    else { s = t = e - NE; }
    int pos = atomicAdd(&cursor[t], 1);
    int2 rec;
    rec.x = s;
    rec.y = __float_as_int(dinv[s] * dinv[t]);
    csr[rowptr[t] + pos] = rec;
}

// ---- W convert to MFMA-fragment-major order, all 3 layers ----
__global__ __launch_bounds__(256) void wcvt_kernel(const float* __restrict__ W0, const float* __restrict__ W1,
                                                   const float* __restrict__ W2, unsigned short* __restrict__ Wsw) {
    int idx = blockIdx.x * 256 + threadIdx.x;  // 3 * 32 frags * 64 lanes = 6144
    if (idx >= 3 * 32 * 64) return;
    int L = idx >> 11;
    int rem = idx & 2047;
    int frag = rem >> 6;         // 0..31  (kc*8 + nt)
    int lane = rem & 63;
    int kc = frag >> 3, nt = frag & 7;
    int m = lane & 15, q = lane >> 4;
    int n = nt * 16 + m;
    int k0 = kc * 32 + q * 8;
    const float* W = (L == 0) ? W0 : (L == 1) ? W1 : W2;
    unsigned int p[4];
#pragma unroll
    for (int j = 0; j < 4; j++) {
        unsigned int b0 = f2bf(W[(size_t)(k0 + 2 * j) * DD + n]);
        unsigned int b1 = f2bf(W[(size_t)(k0 + 2 * j + 1) * DD + n]);
        p[j] = b0 | (b1 << 16);
    }
    uint4 o; o.x = p[0]; o.y = p[1]; o.z = p[2]; o.w = p[3];
    *(uint4*)(Wsw + ((size_t)L * 2048 + (size_t)frag * 64 + lane) * 8) = o;
}

// ---- MFMA GEMM (R11 coalesced design, unchanged) ----
template <bool BF16IN>
__global__ __launch_bounds__(256) void gemm_mfma_kernel(const void* __restrict__ Ain,
                                                        const unsigned short* __restrict__ Wsw,
                                                        const float* __restrict__ normp,
                                                        unsigned short* __restrict__ C) {
    __shared__ unsigned short Atile[64 * 128];  // 16 KB, swizzled 16B chunks
    __shared__ float rep[4][16][68];            // 17.4 KB, per-wave repack
    int tid = threadIdx.x;
    int wslot = tid >> 6;
    int l = tid & 63;
    int m = l & 15;
    int q = l >> 4;
    int rblk = blockIdx.x * 64;

#pragma unroll
    for (int p = 0; p < 4; p++) {
        int rowl = p * 16 + (tid >> 4);
        int c = tid & 15;
        int row = min(rblk + rowl, NN - 1);
        float a[8];
        if (BF16IN) {
            uint4 u = *(const uint4*)((const unsigned short*)Ain + (size_t)row * DD + c * 8);
            a[0] = bflo(u.x); a[1] = bfhi(u.x); a[2] = bflo(u.y); a[3] = bfhi(u.y);
            a[4] = bflo(u.z); a[5] = bfhi(u.z); a[6] = bflo(u.w); a[7] = bfhi(u.w);
        } else {
            const float* Af = (const float*)Ain + (size_t)row * DD + c * 8;
            float4 x0 = *(const float4*)Af;
            float4 x1 = *(const float4*)(Af + 4);
            a[0] = x0.x; a[1] = x0.y; a[2] = x0.z; a[3] = x0.w;
            a[4] = x1.x; a[5] = x1.y; a[6] = x1.z; a[7] = x1.w;
        }
        if (normp) {
#pragma unroll
            for (int j = 0; j < 8; j++) {
                float v = fmaf(a[j], normp[c * 8 + j], normp[128 + c * 8 + j]);
                a[j] = (v >= 0.f) ? v : 0.01f * v;
            }
        }
        unsigned int w0 = f2bf(a[0]) | ((unsigned int)f2bf(a[1]) << 16);
        unsigned int w1 = f2bf(a[2]) | ((unsigned int)f2bf(a[3]) << 16);
        unsigned int w2 = f2bf(a[4]) | ((unsigned int)f2bf(a[5]) << 16);
        unsigned int w3 = f2bf(a[6]) | ((unsigned int)f2bf(a[7]) << 16);
        uint4 wv; wv.x = w0; wv.y = w1; wv.z = w2; wv.w = w3;
        *(uint4*)&Atile[rowl * 128 + ((c ^ (rowl & 15)) * 8)] = wv;
    }
    __syncthreads();

    f32x4 acc[8];
#pragma unroll
    for (int i = 0; i < 8; i++) acc[i] = (f32x4){0.f, 0.f, 0.f, 0.f};
    int rowl_w = wslot * 16 + m;
#pragma unroll
    for (int kc = 0; kc < 4; kc++) {
        short8 af = *(const short8*)&Atile[rowl_w * 128 + (((kc * 4 + q) ^ m) * 8)];
#pragma unroll
        for (int nt = 0; nt < 8; nt++) {
            short8 bf = *(const short8*)(Wsw + ((size_t)(kc * 8 + nt) * 64 + l) * 8);
            acc[nt] = __builtin_amdgcn_mfma_f32_16x16x32_bf16(af, bf, acc[nt], 0, 0, 0);
        }
    }

    int wrow0 = rblk + wslot * 16;
    int r2 = l >> 2, c2 = l & 3;
#pragma unroll
    for (int pass = 0; pass < 2; pass++) {
#pragma unroll
        for (int ntl = 0; ntl < 4; ntl++) {
            f32x4 a = acc[pass * 4 + ntl];
#pragma unroll
            for (int r = 0; r < 4; r++)
                rep[wslot][q * 4 + r][ntl * 16 + m] = a[r];
        }
        const float* tr = &rep[wslot][r2][c2 * 16];
        float4 v0 = *(const float4*)(tr);
        float4 v1 = *(const float4*)(tr + 4);
        float4 v2 = *(const float4*)(tr + 8);
        float4 v3 = *(const float4*)(tr + 12);
        uint4 oA, oB;
        oA.x = f2bf(v0.x) | ((unsigned int)f2bf(v0.y) << 16);
        oA.y = f2bf(v0.z) | ((unsigned int)f2bf(v0.w) << 16);
        oA.z = f2bf(v1.x) | ((unsigned int)f2bf(v1.y) << 16);
        oA.w = f2bf(v1.z) | ((unsigned int)f2bf(v1.w) << 16);
        oB.x = f2bf(v2.x) | ((unsigned int)f2bf(v2.y) << 16);
        oB.y = f2bf(v2.z) | ((unsigned int)f2bf(v2.w) << 16);
        oB.z = f2bf(v3.x) | ((unsigned int)f2bf(v3.y) << 16);
        oB.w = f2bf(v3.z) | ((unsigned int)f2bf(v3.w) << 16);
        int row = wrow0 + r2;
        if (row < NN) {
            unsigned short* cp = C + (size_t)row * DD + pass * 64 + c2 * 16;
            *(uint4*)cp = oA;
            *(uint4*)(cp + 8) = oB;
        }
    }
}

// ---- CSR gather (R10/R11 known-good): one node/wave, unroll 8 ----
__global__ __launch_bounds__(256) void gather_kernel(const unsigned short* __restrict__ xw,
                                                     const int* __restrict__ rowptr,
                                                     const int2* __restrict__ csr,
                                                     unsigned short* __restrict__ agg) {
    int wid = (int)((blockIdx.x * 256 + threadIdx.x) >> 6);
    int l = threadIdx.x & 63;
    if (wid >= NN) return;
    int beg = rowptr[wid], end = rowptr[wid + 1];
    float ax = 0.f, ay = 0.f;
    int i = beg;
    for (; i + 8 <= end; i += 8) {
        unsigned int u[8];
        float c[8];
#pragma unroll
        for (int j = 0; j < 8; j++) {
            int2 r = csr[i + j];
            u[j] = *(const unsigned int*)(xw + (size_t)r.x * DD + 2 * l);
            c[j] = __int_as_float(r.y);
        }
#pragma unroll
        for (int j = 0; j < 8; j++) {
            ax += bflo(u[j]) * c[j];
            ay += bfhi(u[j]) * c[j];
        }
    }
    for (; i + 2 <= end; i += 2) {
        int2 r0 = csr[i], r1 = csr[i + 1];
        unsigned int u0 = *(const unsigned int*)(xw + (size_t)r0.x * DD + 2 * l);
        unsigned int u1 = *(const unsigned int*)(xw + (size_t)r1.x * DD + 2 * l);
        float c0 = __int_as_float(r0.y), c1 = __int_as_float(r1.y);
        ax += bflo(u0) * c0 + bflo(u1) * c1;
        ay += bfhi(u0) * c0 + bfhi(u1) * c1;
    }
    if (i < end) {
        int2 r0 = csr[i];
        unsigned int u0 = *(const unsigned int*)(xw + (size_t)r0.x * DD + 2 * l);
        float c0 = __int_as_float(r0.y);
        ax += bflo(u0) * c0;
        ay += bfhi(u0) * c0;
    }
    ((unsigned int*)(agg + (size_t)wid * DD))[l] = (unsigned int)f2bf(ax) | ((unsigned int)f2bf(ay) << 16);
}

// ---- BN stats stage 1: per-block partials (no atomics). Grid 938. ----
__global__ __launch_bounds__(256) void bnstat1_kernel(const unsigned short* __restrict__ h,
                                                      float* __restrict__ partials) {
    int t = threadIdx.x;
    int rg = t >> 4;       // row group 0..15
    int c  = t & 15;       // feature chunk: features 8c..8c+7
    int rbase = blockIdx.x * 64;
    float s[8], q[8];
#pragma unroll
    for (int j = 0; j < 8; j++) { s[j] = 0.f; q[j] = 0.f; }
#pragma unroll
    for (int p = 0; p < 4; p++) {
        int row = rbase + rg + 16 * p;
        if (row < NN) {
            uint4 u = *(const uint4*)(h + (size_t)row * DD + c * 8);
            float v;
            v = bflo(u.x); s[0] += v; q[0] += v * v;
            v = bfhi(u.x); s[1] += v; q[1] += v * v;
            v = bflo(u.y); s[2] += v; q[2] += v * v;
            v = bfhi(u.y); s[3] += v; q[3] += v * v;
            v = bflo(u.z); s[4] += v; q[4] += v * v;
            v = bfhi(u.z); s[5] += v; q[5] += v * v;
            v = bflo(u.w); s[6] += v; q[6] += v * v;
            v = bfhi(u.w); s[7] += v; q[7] += v * v;
        }
    }
    __shared__ float lds[2][16][128];  // 16 KB
#pragma unroll
    for (int j = 0; j < 8; j++) {
        lds[0][rg][c * 8 + j] = s[j];
        lds[1][rg][c * 8 + j] = q[j];
    }
    __syncthreads();
    int f = t & 127, stat = t >> 7;
    float acc = 0.f;
#pragma unroll
    for (int r = 0; r < 16; r++) acc += lds[stat][r][f];
    partials[(size_t)blockIdx.x * 256 + stat * 128 + f] = acc;  // coalesced 1KB row
}

// ---- BN reduce stage A: 32 blocks each sum ~29 of the 938 partial rows.
// (R13's single-block 938-row sweep ran at VGPR=4, no MLP: 64 us. Split it.)
__global__ __launch_bounds__(256) void bnredA_kernel(const float* __restrict__ partials,
                                                     float* __restrict__ p2) {
    int t = threadIdx.x;
    int b = blockIdx.x;  // 0..RED1-1
    float acc = 0.f;
#pragma unroll 4
    for (int r = b; r < NBK1; r += RED1)
        acc += partials[(size_t)r * 256 + t];   // coalesced, independent
    p2[(size_t)b * 256 + t] = acc;
}

// ---- BN reduce stage B + bnfin: 1 block, 32 fully-unrolled independent loads ----
__global__ __launch_bounds__(256) void bnredB_kernel(const float* __restrict__ p2,
                                                     const float* __restrict__ g,
                                                     const float* __restrict__ be,
                                                     float* __restrict__ normp) {
    int t = threadIdx.x;
    float acc = 0.f;
#pragma unroll
    for (int r = 0; r < RED1; r++)
        acc += p2[(size_t)r * 256 + t];
    __shared__ float tot[256];
    tot[t] = acc;
    __syncthreads();
    if (t < 128) {
        float sm = tot[t], sq = tot[128 + t];
        const float invN = 1.0f / (float)NN;
        float mu = sm * invN;
        float var = sq * invN - mu * mu;
        float sc = rsqrtf(var + 1e-5f) * g[t];
        normp[t] = sc;
        normp[128 + t] = be[t] - mu * sc;
    }
}

// ---- final: out_fp32 = bf16(agg)*scale+shift ----
__global__ __launch_bounds__(256) void bnapply_kernel(const unsigned short* __restrict__ h,
                                                      const float* __restrict__ normp,
                                                      float* __restrict__ out) {
    int idx = blockIdx.x * 256 + threadIdx.x;
    if (idx >= NN * DD / 4) return;
    int d = (idx * 4) & 127;
    uint2 u = *(const uint2*)(h + idx * 4);
    float4 sc = *(const float4*)&normp[d];
    float4 sh = *(const float4*)&normp[128 + d];
    float4 o;
    o.x = fmaf(bflo(u.x), sc.x, sh.x);
    o.y = fmaf(bfhi(u.x), sc.y, sh.y);
    o.z = fmaf(bflo(u.y), sc.z, sh.z);
    o.w = fmaf(bfhi(u.y), sc.w, sh.w);
    *(float4*)&out[idx * 4] = o;
}

extern "C" void kernel_launch(void* const* d_in, const int* in_sizes, int n_in,
                              void* d_out, int out_size, void* d_ws, size_t ws_size,
                              hipStream_t stream) {
    const float* x = (const float*)d_in[0];
    const int* ei = (const int*)d_in[1];
    const int* srcp = ei;
    const int* dstp = ei + NE;
    const float* w[3]  = {(const float*)d_in[2], (const float*)d_in[6],  (const float*)d_in[10]};
    const float* g[3]  = {(const float*)d_in[4], (const float*)d_in[8],  (const float*)d_in[12]};
    const float* be[3] = {(const float*)d_in[5], (const float*)d_in[9],  (const float*)d_in[13]};

    // workspace layout (~44 MB), all chunks 16-B aligned
    unsigned short* xwb  = (unsigned short*)d_ws;        // bf16 xw  [NN*DD]
    unsigned short* aggb = xwb + (size_t)NN * DD;        // bf16 agg [NN*DD]
    int* deg    = (int*)(aggb + (size_t)NN * DD);        // [NN]  (one memset: deg+cursor)
    int* cursor = deg + NN;                              // [NN]
    int* rowptr = cursor + NN;                           // [NN+16]
    float* dinv = (float*)(rowptr + NN + 16);            // [NN]
    float* ss   = dinv + NN;                             // [3*256] scale/shift per layer
    int* spart  = (int*)(ss + 3 * 256);                  // [256] scan partials
    int* blockoff = spart + 256;                         // [256]
    float* bnp  = (float*)(blockoff + 256);              // [NBK1*256] bn partials
    float* bnp2 = bnp + (size_t)NBK1 * 256;              // [RED1*256] stage-2 partials
    unsigned short* Wsw = (unsigned short*)(bnp2 + RED1 * 256);  // [3*128*128]
    int2* csr = (int2*)(Wsw + 3 * DD * DD);              // [NTOT] packed {src, coef}
    float* out = (float*)d_out;

    // ---- CSR build (once; edge_index constant across layers) ----
    hipMemsetAsync(deg, 0, 2 * NN * sizeof(int), stream);        // deg + cursor
    deg_kernel<<<(NE + 255) / 256, 256, 0, stream>>>(dstp, deg);
    scanA_kernel<<<NB, 256, 0, stream>>>(deg, spart, dinv);
    scanB_kernel<<<1, 256, 0, stream>>>(spart, blockoff, rowptr);
    scanC_kernel<<<NB, 256, 0, stream>>>(deg, blockoff, rowptr);
    fill_kernel<<<(NTOT + 255) / 256, 256, 0, stream>>>(srcp, dstp, rowptr, cursor, dinv, csr);
    wcvt_kernel<<<24, 256, 0, stream>>>(w[0], w[1], w[2], Wsw);

    const int GATHER_GRID = (NN + 3) / 4;       // 15000 (one node per wave)
    for (int L = 0; L < 3; ++L) {
        const float* normp = (L == 0) ? nullptr : (ss + (L - 1) * 256);
        if (L == 0)
            gemm_mfma_kernel<false><<<NBK1, 256, 0, stream>>>(x, Wsw, normp, xwb);
        else
            gemm_mfma_kernel<true><<<NBK1, 256, 0, stream>>>(aggb, Wsw + (size_t)L * DD * DD, normp, xwb);
        gather_kernel<<<GATHER_GRID, 256, 0, stream>>>(xwb, rowptr, csr, aggb);
        bnstat1_kernel<<<NBK1, 256, 0, stream>>>(aggb, bnp);
        bnredA_kernel<<<RED1, 256, 0, stream>>>(bnp, bnp2);
        bnredB_kernel<<<1, 256, 0, stream>>>(bnp2, g[L], be[L], ss + L * 256);
        if (L == 2)
            bnapply_kernel<<<(NN * DD / 4 + 255) / 256, 256, 0, stream>>>(aggb, ss + L * 256, out);
    }
}